// Round 1
// baseline (1092.394 us; speedup 1.0000x reference)
//
#include <hip/hip_runtime.h>
#include <hip/hip_bf16.h>
#include <math.h>

#define B_   4
#define C_   256
#define L_   8192
#define NH   8
#define HD   32
#define WIN  256
#define STR  192
#define NWIN 43
#define HID  1024

__device__ inline float gelu_exact(float v) {
    return 0.5f * v * (1.0f + erff(v * 0.70710678118654752f));
}

// ---------------------------------------------------------------------------
// Tiled fp32 GEMM:  out[b,o,l] = sum_c W[o,c] * X[b,c,l]  + mode-specific epilogue
// MODE 0: qkv   (M=768,  K=256)  X = x + pos           -> scatter to q/k/v (B,NH,L,HD)
// MODE 1: proj  (M=256,  K=256)  X = attn * invcnt(l)  -> + bias + residual(x) -> y
// MODE 2: mlp1  (M=1024, K=256)  X = y                 -> gelu(.+bias) -> h
// MODE 3: mlp2  (M=256,  K=1024) X = h                 -> .+bias -> d_out (pre-norm)
// ---------------------------------------------------------------------------
template<int MODE>
__global__ __launch_bounds__(256)
void gemm_k(const float* __restrict__ W, const float* __restrict__ X,
            const float* __restrict__ bias, const float* __restrict__ extra,
            float* __restrict__ out)
{
    constexpr int K = (MODE == 3) ? 1024 : 256;
    constexpr int M = (MODE == 0) ? 768 : (MODE == 2) ? 1024 : 256;

    __shared__ float Ws[16][72];   // [c_local][o_local], padded (272B rows, 16B-aligned)
    __shared__ float Xs[16][64];   // [c_local][l_local]

    const int b  = blockIdx.z;
    const int o0 = blockIdx.y * 64;
    const int l0 = blockIdx.x * 64;
    const int t  = threadIdx.x;
    const int tx = t & 15, ty = t >> 4;

    const float* Xb = X + (size_t)b * K * L_;

    float acc[4][4] = {};

    const int wo = o0 + (t >> 2);      // W row this thread stages
    const int wc = (t & 3) * 4;        // W col group
    const int xc = t >> 4;             // X row this thread stages
    const int xl = (t & 15) * 4;       // X col group

    for (int c0 = 0; c0 < K; c0 += 16) {
        float4 wv = *(const float4*)&W[(size_t)wo * K + c0 + wc];
        float4 xv = *(const float4*)&Xb[(size_t)(c0 + xc) * L_ + l0 + xl];
        if (MODE == 0) {
            float p = extra[c0 + xc];   // pos[c]
            xv.x += p; xv.y += p; xv.z += p; xv.w += p;
        }
        if (MODE == 1) {
            int lb = l0 + xl;
            #pragma unroll
            for (int comp = 0; comp < 4; ++comp) {
                int l = lb + comp;
                int nhi = l / STR;
                int nlo = (l >= WIN) ? ((l - WIN) / STR + 1) : 0;
                (&xv.x)[comp] *= 1.0f / (float)(nhi - nlo + 1);
            }
        }
        __syncthreads();
        Ws[wc + 0][t >> 2] = wv.x;
        Ws[wc + 1][t >> 2] = wv.y;
        Ws[wc + 2][t >> 2] = wv.z;
        Ws[wc + 3][t >> 2] = wv.w;
        *(float4*)&Xs[xc][xl] = xv;
        __syncthreads();
        #pragma unroll
        for (int kk = 0; kk < 16; ++kk) {
            const float4 a4 = *(const float4*)&Ws[kk][ty * 4];
            const float4 b4 = *(const float4*)&Xs[kk][tx * 4];
            const float ar[4] = {a4.x, a4.y, a4.z, a4.w};
            const float br[4] = {b4.x, b4.y, b4.z, b4.w};
            #pragma unroll
            for (int i = 0; i < 4; ++i)
                #pragma unroll
                for (int j = 0; j < 4; ++j)
                    acc[i][j] = fmaf(ar[i], br[j], acc[i][j]);
        }
    }

    if constexpr (MODE == 0) {
        // restage through LDS so (B,NH,L,HD) stores are coalesced float4
        __shared__ float Ts[64][68];   // [o_local][l_local], 272B rows
        #pragma unroll
        for (int i = 0; i < 4; ++i) {
            float bv = bias[o0 + ty * 4 + i];
            float4 vv;
            vv.x = acc[i][0] + bv; vv.y = acc[i][1] + bv;
            vv.z = acc[i][2] + bv; vv.w = acc[i][3] + bv;
            *(float4*)&Ts[ty * 4 + i][tx * 4] = vv;
        }
        __syncthreads();
        const int part = o0 >> 8;              // 0=q 1=k 2=v
        const int h0   = (o0 & 255) >> 5;      // first head in this 64-row tile
        float* dst = out + (size_t)part * ((size_t)B_ * C_ * L_);
        #pragma unroll
        for (int rep = 0; rep < 4; ++rep) {
            int idx = t + rep * 256;           // 0..1023 float4s
            int hb  = idx >> 9;                // head-block 0/1
            int rem = idx & 511;
            int r   = rem >> 3;                // l_local
            int d4  = (rem & 7) * 4;           // d group
            int oc  = hb * 32 + d4;
            float4 vv;
            vv.x = Ts[oc + 0][r]; vv.y = Ts[oc + 1][r];
            vv.z = Ts[oc + 2][r]; vv.w = Ts[oc + 3][r];
            *(float4*)&dst[((size_t)(b * NH + h0 + hb) * L_ + (l0 + r)) * HD + d4] = vv;
        }
    } else {
        #pragma unroll
        for (int i = 0; i < 4; ++i) {
            const int o = o0 + ty * 4 + i;
            const float bv = bias[o];
            float4 vv;
            vv.x = acc[i][0] + bv; vv.y = acc[i][1] + bv;
            vv.z = acc[i][2] + bv; vv.w = acc[i][3] + bv;
            if (MODE == 1) {
                float4 rv = *(const float4*)&extra[((size_t)b * C_ + o) * L_ + l0 + tx * 4];
                vv.x += rv.x; vv.y += rv.y; vv.z += rv.z; vv.w += rv.w;
            }
            if (MODE == 2) {
                vv.x = gelu_exact(vv.x); vv.y = gelu_exact(vv.y);
                vv.z = gelu_exact(vv.z); vv.w = gelu_exact(vv.w);
            }
            *(float4*)&out[((size_t)b * M + o) * L_ + l0 + tx * 4] = vv;
        }
    }
}

// ---------------------------------------------------------------------------
// Windowed attention: one block per (window n, head h, batch b).
// Thread t owns query row t. Online softmax over the 256-key window.
// Scatter-add into attn buffer (B,C,L) with atomics (<=2 adds/site).
// ---------------------------------------------------------------------------
__global__ __launch_bounds__(256)
void attn_k(const float* __restrict__ q, const float* __restrict__ k,
            const float* __restrict__ v, float* __restrict__ outbuf)
{
    __shared__ float Ks[WIN][HD];
    __shared__ float Vs[WIN][HD];
    const int n = blockIdx.x, h = blockIdx.y, b = blockIdx.z;
    const int start = n * STR;
    const int t = threadIdx.x;
    const size_t headbase = (size_t)(b * NH + h) * L_ * HD;

    {
        const int d4 = (t & 7) * 4;
        const int j0 = t >> 3;
        #pragma unroll
        for (int rep = 0; rep < 8; ++rep) {
            int j = j0 + rep * 32;
            int l = start + j; if (l > L_ - 1) l = L_ - 1;
            *(float4*)&Ks[j][d4] = *(const float4*)&k[headbase + (size_t)l * HD + d4];
            *(float4*)&Vs[j][d4] = *(const float4*)&v[headbase + (size_t)l * HD + d4];
        }
    }
    __syncthreads();

    const int lq = start + t;
    int jmax = L_ - start; if (jmax > WIN) jmax = WIN;

    float qr[HD];
    {
        int lqc = lq < L_ ? lq : L_ - 1;
        #pragma unroll
        for (int i = 0; i < 8; ++i) {
            float4 qv = *(const float4*)&q[headbase + (size_t)lqc * HD + i * 4];
            qr[i*4+0] = qv.x; qr[i*4+1] = qv.y; qr[i*4+2] = qv.z; qr[i*4+3] = qv.w;
        }
    }

    float m = -INFINITY, lsum = 0.f;
    float O[HD] = {};
    const float scale = 0.17677669529663687f;  // 1/sqrt(32)

    for (int j = 0; j < jmax; ++j) {
        float s = 0.f;
        #pragma unroll
        for (int d4 = 0; d4 < HD; d4 += 4) {
            float4 kv = *(const float4*)&Ks[j][d4];
            s += qr[d4] * kv.x + qr[d4+1] * kv.y + qr[d4+2] * kv.z + qr[d4+3] * kv.w;
        }
        s *= scale;
        float nm = fmaxf(m, s);
        float a = __expf(m - nm);   // first iter: exp(-inf)=0
        float p = __expf(s - nm);
        lsum = lsum * a + p;
        m = nm;
        #pragma unroll
        for (int d4 = 0; d4 < HD; d4 += 4) {
            float4 vv = *(const float4*)&Vs[j][d4];
            O[d4+0] = O[d4+0] * a + p * vv.x;
            O[d4+1] = O[d4+1] * a + p * vv.y;
            O[d4+2] = O[d4+2] * a + p * vv.z;
            O[d4+3] = O[d4+3] * a + p * vv.w;
        }
    }

    if (lq < L_) {
        float inv = 1.0f / lsum;
        #pragma unroll
        for (int d = 0; d < HD; ++d)
            atomicAdd(&outbuf[((size_t)(b * C_ + h * HD + d)) * L_ + lq], O[d] * inv);
    }
}

// ---------------------------------------------------------------------------
// Instance norm over L per (b,c) row; optional residual add; in-place safe.
// ---------------------------------------------------------------------------
__global__ __launch_bounds__(256)
void norm_k(const float* __restrict__ src, const float* __restrict__ add,
            float* __restrict__ dst)
{
    const int row = blockIdx.x;                  // b*C + c
    const float* s = src + (size_t)row * L_;
    const int t = threadIdx.x;
    float4 vals[8];
    float sum = 0.f, ssq = 0.f;
    #pragma unroll
    for (int i = 0; i < 8; ++i) {
        float4 vv = *(const float4*)&s[t * 4 + i * 1024];
        vals[i] = vv;
        sum += (vv.x + vv.y) + (vv.z + vv.w);
        ssq += vv.x*vv.x + vv.y*vv.y + vv.z*vv.z + vv.w*vv.w;
    }
    #pragma unroll
    for (int off = 32; off > 0; off >>= 1) {
        sum += __shfl_down(sum, off);
        ssq += __shfl_down(ssq, off);
    }
    __shared__ float rbuf[8];
    __shared__ float s_mean, s_rstd;
    if ((t & 63) == 0) { rbuf[t >> 6] = sum; rbuf[4 + (t >> 6)] = ssq; }
    __syncthreads();
    if (t == 0) {
        float a  = (rbuf[0] + rbuf[1]) + (rbuf[2] + rbuf[3]);
        float q2 = (rbuf[4] + rbuf[5]) + (rbuf[6] + rbuf[7]);
        float mean = a * (1.0f / L_);
        float var  = q2 * (1.0f / L_) - mean * mean;
        s_mean = mean;
        s_rstd = rsqrtf(var + 1e-5f);
    }
    __syncthreads();
    const float mean = s_mean, rstd = s_rstd;
    float* d = dst + (size_t)row * L_;
    const float* ar = add ? add + (size_t)row * L_ : nullptr;
    #pragma unroll
    for (int i = 0; i < 8; ++i) {
        float4 vv = vals[i];
        vv.x = (vv.x - mean) * rstd;
        vv.y = (vv.y - mean) * rstd;
        vv.z = (vv.z - mean) * rstd;
        vv.w = (vv.w - mean) * rstd;
        if (ar) {
            float4 av = *(const float4*)&ar[t * 4 + i * 1024];
            vv.x += av.x; vv.y += av.y; vv.z += av.z; vv.w += av.w;
        }
        *(float4*)&d[t * 4 + i * 1024] = vv;
    }
}

extern "C" void kernel_launch(void* const* d_in, const int* in_sizes, int n_in,
                              void* d_out, int out_size, void* d_ws, size_t ws_size,
                              hipStream_t stream) {
    const float* x      = (const float*)d_in[0];
    const float* pos    = (const float*)d_in[1];
    const float* w_qkv  = (const float*)d_in[2];
    const float* b_qkv  = (const float*)d_in[3];
    const float* w_out  = (const float*)d_in[4];
    const float* b_out  = (const float*)d_in[5];
    const float* w_mlp1 = (const float*)d_in[6];
    const float* b_mlp1 = (const float*)d_in[7];
    const float* w_mlp2 = (const float*)d_in[8];
    const float* b_mlp2 = (const float*)d_in[9];
    float* out = (float*)d_out;
    float* ws  = (float*)d_ws;

    const size_t SZ = (size_t)B_ * C_ * L_;   // 8M floats = 32MB
    float* qb   = ws;              // q,k,v : [0, 3*SZ)
    float* attn = ws + 3 * SZ;     // [3SZ, 4SZ)
    float* y    = ws + 4 * SZ;     // [4SZ, 5SZ)
    float* hbuf = ws;              // h overlays [0, 4SZ) after q/k/v/attn are dead
    // total ws use: 5*SZ floats = 160 MB

    hipMemsetAsync(attn, 0, SZ * sizeof(float), stream);

    gemm_k<0><<<dim3(L_/64, 768/64,  B_), 256, 0, stream>>>(w_qkv, x, b_qkv, pos, qb);
    attn_k  <<<dim3(NWIN, NH, B_),        256, 0, stream>>>(qb, qb + SZ, qb + 2*SZ, attn);
    gemm_k<1><<<dim3(L_/64, 256/64,  B_), 256, 0, stream>>>(w_out, attn, b_out, x, y);
    norm_k  <<<dim3(B_*C_),               256, 0, stream>>>(y, nullptr, y);
    gemm_k<2><<<dim3(L_/64, 1024/64, B_), 256, 0, stream>>>(w_mlp1, y, b_mlp1, nullptr, hbuf);
    gemm_k<3><<<dim3(L_/64, 256/64,  B_), 256, 0, stream>>>(w_mlp2, hbuf, b_mlp2, nullptr, out);
    norm_k  <<<dim3(B_*C_),               256, 0, stream>>>(out, y, out);
}

// Round 2
// 808.397 us; speedup vs baseline: 1.3513x; 1.3513x over previous
//
#include <hip/hip_runtime.h>
#include <hip/hip_bf16.h>
#include <math.h>

#define B_   4
#define C_   256
#define L_   8192
#define NH   8
#define HD   32
#define WIN  256
#define STR  192
#define NWIN 43
#define HID  1024

typedef short short8 __attribute__((ext_vector_type(8)));
typedef float f32x4  __attribute__((ext_vector_type(4)));

typedef __attribute__((address_space(3))) unsigned int       as3_u32;
typedef __attribute__((address_space(1))) const unsigned int as1_u32;

__device__ __forceinline__ void gll16(const void* g, void* l) {
    __builtin_amdgcn_global_load_lds((as1_u32*)g, (as3_u32*)l, 16, 0, 0);
}

__device__ __forceinline__ short f2b(float f) {          // f32 -> bf16 RNE
    unsigned u = __builtin_bit_cast(unsigned, f);
    u += 0x7fffu + ((u >> 16) & 1u);
    return (short)(u >> 16);
}
__device__ __forceinline__ float b2f(short s) {          // bf16 -> f32
    return __builtin_bit_cast(float, (unsigned)((unsigned short)s) << 16);
}
__device__ __forceinline__ float gelu_exact(float v) {
    return 0.5f * v * (1.0f + erff(v * 0.70710678118654752f));
}

// ---------------------------------------------------------------------------
// bf16 MFMA GEMM: out[b,o,l] = sum_c W[o,c] * X[b,l,c]   (X stored K-contiguous)
// 128x128 tile, BK=32, 4 waves (2x2), each wave 64x64 = 4x4 frags of 16x16x32.
// LDS tiles [128][32] bf16, chunk-swizzled: phys_chunk = log_chunk ^ ((row>>1)&3),
// applied via pre-swizzled global source (LDS dest stays linear for global_load_lds).
// MODE 0: qkv  (M=768,K=256)  B=xp_t bf16          -> +bias, bf16 q/k/v head layout
// MODE 1: proj (M=256,K=256)  B=attn f32 (reg-stage+convert) -> +bias+resid, f32 y
// MODE 2: mlp1 (M=1024,K=256) B=y_t bf16           -> gelu(+bias), bf16 h_t [L][HID]
// MODE 3: mlp2 (M=256,K=1024) B=h_t bf16           -> +bias, f32 d_out
// ---------------------------------------------------------------------------
template<int MODE>
__global__ __launch_bounds__(256)
void mgemm(const short* __restrict__ Wb, const void* __restrict__ Xsrc,
           const float* __restrict__ bias, const float* __restrict__ resid,
           void* __restrict__ outp)
{
    constexpr int K = (MODE == 3) ? 1024 : 256;
    constexpr int M = (MODE == 0) ? 768 : (MODE == 2) ? 1024 : 256;
    constexpr int LDSZ = (MODE == 0 || MODE == 2) ? 34816 : 16384;
    __shared__ __align__(16) char lds[LDSZ];

    const int t    = threadIdx.x;
    const int lane = t & 63, wid = t >> 6;
    const int wm   = wid >> 1, wn = wid & 1;
    const int b    = blockIdx.z;
    const int o0   = blockIdx.y * 128;
    const int l0   = blockIdx.x * 128;

    const int l15 = lane & 15, kb = lane >> 4;
    const int swz = kb ^ ((l15 >> 1) & 3);
    const int offA = (wm * 64 + l15) * 64 + swz * 16;          // byte offsets
    const int offB = 8192 + (wn * 64 + l15) * 64 + swz * 16;

    f32x4 acc[4][4] = {};

    for (int c0 = 0; c0 < K; c0 += 32) {
        __syncthreads();   // previous iteration's frag reads complete
        // ---- stage A (weights, bf16, global_load_lds) ----
        #pragma unroll
        for (int it = 0; it < 2; ++it) {
            int r = (t >> 2) + it * 64;
            int clog = (t & 3) ^ ((r >> 1) & 3);
            const short* src = Wb + (size_t)(o0 + r) * K + c0 + clog * 8;
            gll16(src, lds + (wid * 64 + it * 256) * 16);
        }
        // ---- stage B ----
        if (MODE == 1) {   // f32 source, reg-stage + convert
            const float* Xf = (const float*)Xsrc + (size_t)b * L_ * C_;
            #pragma unroll
            for (int it = 0; it < 2; ++it) {
                int r = (t >> 2) + it * 64;
                int clog = (t & 3) ^ ((r >> 1) & 3);
                const float* s2 = Xf + (size_t)(l0 + r) * C_ + c0 + clog * 8;
                float4 va = *(const float4*)s2;
                float4 vb = *(const float4*)(s2 + 4);
                short8 o;
                o[0] = f2b(va.x); o[1] = f2b(va.y); o[2] = f2b(va.z); o[3] = f2b(va.w);
                o[4] = f2b(vb.x); o[5] = f2b(vb.y); o[6] = f2b(vb.z); o[7] = f2b(vb.w);
                *(short8*)(lds + 8192 + (t + it * 256) * 16) = o;
            }
        } else {
            const short* Xb = (const short*)Xsrc + (size_t)b * L_ * K;
            #pragma unroll
            for (int it = 0; it < 2; ++it) {
                int r = (t >> 2) + it * 64;
                int clog = (t & 3) ^ ((r >> 1) & 3);
                const short* src = Xb + (size_t)(l0 + r) * K + c0 + clog * 8;
                gll16(src, lds + 8192 + (wid * 64 + it * 256) * 16);
            }
        }
        __syncthreads();   // drains vmcnt+lgkmcnt
        // ---- compute ----
        short8 af[4], bf[4];
        #pragma unroll
        for (int i = 0; i < 4; ++i) af[i] = *(const short8*)(lds + offA + i * 1024);
        #pragma unroll
        for (int j = 0; j < 4; ++j) bf[j] = *(const short8*)(lds + offB + j * 1024);
        #pragma unroll
        for (int i = 0; i < 4; ++i)
            #pragma unroll
            for (int j = 0; j < 4; ++j)
                acc[i][j] = __builtin_amdgcn_mfma_f32_16x16x32_bf16(af[i], bf[j], acc[i][j], 0, 0, 0);
    }

    const int orow = (lane >> 4) * 4;

    if constexpr (MODE == 1 || MODE == 3) {
        float* out = (float*)outp;
        #pragma unroll
        for (int i = 0; i < 4; ++i) {
            #pragma unroll
            for (int r = 0; r < 4; ++r) {
                const int o = o0 + wm * 64 + i * 16 + orow + r;
                const float bv = bias[o];
                #pragma unroll
                for (int j = 0; j < 4; ++j) {
                    const int l = l0 + wn * 64 + j * 16 + l15;
                    float v = acc[i][j][r] + bv;
                    if (MODE == 1) v += resid[((size_t)b * C_ + o) * L_ + l];
                    out[((size_t)b * M + o) * L_ + l] = v;
                }
            }
        }
    } else {
        // restage 128x128 tile to LDS (bf16, [l_loc][o_loc], pitch 136) for coalesced stores
        __syncthreads();
        short* Ts = (short*)lds;
        #pragma unroll
        for (int i = 0; i < 4; ++i) {
            #pragma unroll
            for (int r = 0; r < 4; ++r) {
                const int ol = wm * 64 + i * 16 + orow + r;
                const float bv = bias[o0 + ol];
                #pragma unroll
                for (int j = 0; j < 4; ++j) {
                    const int ll = wn * 64 + j * 16 + l15;
                    float v = acc[i][j][r] + bv;
                    if (MODE == 2) v = gelu_exact(v);
                    Ts[ll * 136 + ol] = f2b(v);
                }
            }
        }
        __syncthreads();
        if constexpr (MODE == 2) {
            short* ht = (short*)outp;   // [B][L][HID]
            #pragma unroll
            for (int it = 0; it < 8; ++it) {
                int idx = t + it * 256;
                int ll = idx >> 4, ck = (idx & 15) * 8;
                short8 v = *(const short8*)(Ts + ll * 136 + ck);
                *(short8*)(ht + ((size_t)b * L_ + l0 + ll) * HID + o0 + ck) = v;
            }
        } else {              // MODE 0: q/k/v bf16 [part][b][h][l][d]
            short* qkv = (short*)outp;
            #pragma unroll
            for (int it = 0; it < 8; ++it) {
                int idx = t + it * 256;
                int hb = idx >> 9, rem = idx & 511;
                int ll = rem >> 2, dk = (rem & 3) * 8;
                short8 v = *(const short8*)(Ts + ll * 136 + hb * 32 + dk);
                int og = o0 + hb * 32;
                int part = og >> 8, h = (og & 255) >> 5;
                short* dst = qkv + (size_t)part * ((size_t)B_ * NH * L_ * HD)
                           + (((size_t)(b * NH + h) * L_ + l0 + ll) * HD + dk);
                *(short8*)dst = v;
            }
        }
    }
}

// ---------------------------------------------------------------------------
// Windowed attention (fp32 compute, bf16 in). One block per (window,head,batch).
// Epilogue folds softmax 1/lsum AND the 1/count window-average; atomicAdd into
// f32 attn buffer laid out [B][L][C] (K-contiguous for the proj GEMM).
// ---------------------------------------------------------------------------
__global__ __launch_bounds__(256)
void attn_k(const short* __restrict__ q, const short* __restrict__ k,
            const short* __restrict__ v, float* __restrict__ outbuf)
{
    __shared__ float Ks[WIN][HD];
    __shared__ float Vs[WIN][HD];
    const int n = blockIdx.x, h = blockIdx.y, b = blockIdx.z;
    const int start = n * STR;
    const int t = threadIdx.x;
    const size_t headbase = (size_t)(b * NH + h) * L_ * HD;

    {
        const int d8 = (t & 3) * 8;
        const int j0 = t >> 2;
        #pragma unroll
        for (int rep = 0; rep < 4; ++rep) {
            int j = j0 + rep * 64;
            int l = start + j; if (l > L_ - 1) l = L_ - 1;
            short8 kv = *(const short8*)&k[headbase + (size_t)l * HD + d8];
            short8 vv = *(const short8*)&v[headbase + (size_t)l * HD + d8];
            #pragma unroll
            for (int e = 0; e < 8; ++e) {
                Ks[j][d8 + e] = b2f(kv[e]);
                Vs[j][d8 + e] = b2f(vv[e]);
            }
        }
    }
    __syncthreads();

    const int lq = start + t;
    int jmax = L_ - start; if (jmax > WIN) jmax = WIN;

    float qr[HD];
    {
        int lqc = lq < L_ ? lq : L_ - 1;
        #pragma unroll
        for (int i = 0; i < 4; ++i) {
            short8 qv = *(const short8*)&q[headbase + (size_t)lqc * HD + i * 8];
            #pragma unroll
            for (int e = 0; e < 8; ++e) qr[i * 8 + e] = b2f(qv[e]);
        }
    }

    float m = -INFINITY, lsum = 0.f;
    float O[HD] = {};
    const float scale = 0.17677669529663687f;  // 1/sqrt(32)

    for (int j = 0; j < jmax; ++j) {
        float s = 0.f;
        #pragma unroll
        for (int d = 0; d < HD; d += 4)
            s += qr[d] * Ks[j][d] + qr[d+1] * Ks[j][d+1] + qr[d+2] * Ks[j][d+2] + qr[d+3] * Ks[j][d+3];
        s *= scale;
        float nm = fmaxf(m, s);
        float a = __expf(m - nm);
        float p = __expf(s - nm);
        lsum = lsum * a + p;
        m = nm;
        #pragma unroll
        for (int d = 0; d < HD; ++d)
            O[d] = O[d] * a + p * Vs[j][d];
    }

    if (lq < L_) {
        int nhi = lq / STR;
        int nlo = (lq >= WIN) ? ((lq - WIN) / STR + 1) : 0;
        float sc = (1.0f / lsum) / (float)(nhi - nlo + 1);
        float* dst = &outbuf[((size_t)b * L_ + lq) * C_ + h * HD];
        #pragma unroll
        for (int d = 0; d < HD; ++d)
            atomicAdd(&dst[d], O[d] * sc);
    }
}

// ---------------------------------------------------------------------------
// Transpose+convert: f32 [B][C][L] (+optional pos[c]) -> bf16 [B][L][C]
// ---------------------------------------------------------------------------
__global__ __launch_bounds__(256)
void prep_k(const float* __restrict__ in, const float* __restrict__ pos,
            short* __restrict__ outT)
{
    __shared__ float T[64][65];
    const int b = blockIdx.z, c0 = blockIdx.y * 64, l0 = blockIdx.x * 64;
    const int t = threadIdx.x;
    #pragma unroll
    for (int it = 0; it < 4; ++it) {
        int idx = t + it * 256;
        int c = idx >> 4, l4 = (idx & 15) * 4;
        float4 v = *(const float4*)&in[((size_t)b * C_ + c0 + c) * L_ + l0 + l4];
        float p = pos ? pos[c0 + c] : 0.f;
        T[c][l4 + 0] = v.x + p; T[c][l4 + 1] = v.y + p;
        T[c][l4 + 2] = v.z + p; T[c][l4 + 3] = v.w + p;
    }
    __syncthreads();
    #pragma unroll
    for (int it = 0; it < 2; ++it) {
        int idx = t + it * 256;
        int l = idx >> 3, ck = (idx & 7) * 8;
        short8 o;
        #pragma unroll
        for (int j = 0; j < 8; ++j) o[j] = f2b(T[ck + j][l]);
        *(short8*)&outT[((size_t)b * L_ + l0 + l) * C_ + c0 + ck] = o;
    }
}

// weight convert f32->bf16, 4 segments in one kernel
__global__ __launch_bounds__(256)
void wconv_k(const float* a, const float* b, const float* c, const float* d,
             short* oa, short* ob, short* oc, short* od)
{
    int i = (blockIdx.x * 256 + threadIdx.x) * 8;
    const float* s; short* o; int off;
    if (i < 196608)      { s = a; o = oa; off = i; }
    else if (i < 262144) { s = b; o = ob; off = i - 196608; }
    else if (i < 524288) { s = c; o = oc; off = i - 262144; }
    else                 { s = d; o = od; off = i - 524288; }
    float4 v0 = *(const float4*)(s + off);
    float4 v1 = *(const float4*)(s + off + 4);
    short8 r;
    r[0] = f2b(v0.x); r[1] = f2b(v0.y); r[2] = f2b(v0.z); r[3] = f2b(v0.w);
    r[4] = f2b(v1.x); r[5] = f2b(v1.y); r[6] = f2b(v1.z); r[7] = f2b(v1.w);
    *(short8*)(o + off) = r;
}

// ---------------------------------------------------------------------------
// Instance norm over L per (b,c) row; optional residual add; in-place safe.
// ---------------------------------------------------------------------------
__global__ __launch_bounds__(256)
void norm_k(const float* __restrict__ src, const float* __restrict__ add,
            float* __restrict__ dst)
{
    const int row = blockIdx.x;
    const float* s = src + (size_t)row * L_;
    const int t = threadIdx.x;
    float4 vals[8];
    float sum = 0.f, ssq = 0.f;
    #pragma unroll
    for (int i = 0; i < 8; ++i) {
        float4 vv = *(const float4*)&s[t * 4 + i * 1024];
        vals[i] = vv;
        sum += (vv.x + vv.y) + (vv.z + vv.w);
        ssq += vv.x*vv.x + vv.y*vv.y + vv.z*vv.z + vv.w*vv.w;
    }
    #pragma unroll
    for (int off = 32; off > 0; off >>= 1) {
        sum += __shfl_down(sum, off);
        ssq += __shfl_down(ssq, off);
    }
    __shared__ float rbuf[8];
    __shared__ float s_mean, s_rstd;
    if ((t & 63) == 0) { rbuf[t >> 6] = sum; rbuf[4 + (t >> 6)] = ssq; }
    __syncthreads();
    if (t == 0) {
        float a  = (rbuf[0] + rbuf[1]) + (rbuf[2] + rbuf[3]);
        float q2 = (rbuf[4] + rbuf[5]) + (rbuf[6] + rbuf[7]);
        float mean = a * (1.0f / L_);
        float var  = q2 * (1.0f / L_) - mean * mean;
        s_mean = mean;
        s_rstd = rsqrtf(var + 1e-5f);
    }
    __syncthreads();
    const float mean = s_mean, rstd = s_rstd;
    float* d = dst + (size_t)row * L_;
    const float* ar = add ? add + (size_t)row * L_ : nullptr;
    #pragma unroll
    for (int i = 0; i < 8; ++i) {
        float4 vv = vals[i];
        vv.x = (vv.x - mean) * rstd;
        vv.y = (vv.y - mean) * rstd;
        vv.z = (vv.z - mean) * rstd;
        vv.w = (vv.w - mean) * rstd;
        if (ar) {
            float4 av = *(const float4*)&ar[t * 4 + i * 1024];
            vv.x += av.x; vv.y += av.y; vv.z += av.z; vv.w += av.w;
        }
        *(float4*)&d[t * 4 + i * 1024] = vv;
    }
}

extern "C" void kernel_launch(void* const* d_in, const int* in_sizes, int n_in,
                              void* d_out, int out_size, void* d_ws, size_t ws_size,
                              hipStream_t stream) {
    const float* x      = (const float*)d_in[0];
    const float* pos    = (const float*)d_in[1];
    const float* w_qkv  = (const float*)d_in[2];
    const float* b_qkv  = (const float*)d_in[3];
    const float* w_out  = (const float*)d_in[4];
    const float* b_out  = (const float*)d_in[5];
    const float* w_mlp1 = (const float*)d_in[6];
    const float* b_mlp1 = (const float*)d_in[7];
    const float* w_mlp2 = (const float*)d_in[8];
    const float* b_mlp2 = (const float*)d_in[9];
    float* out = (float*)d_out;

    constexpr size_t MB = 1u << 20;
    char* w = (char*)d_ws;
    short* xp_t  = (short*)(w);             // 16MB, dead after gemm0
    short* qb    = (short*)(w + 16 * MB);   // 48MB q/k/v, dead after attn_k
    float* attnf = (float*)(w + 64 * MB);   // 32MB, dead after gemm1
    float* yb    = (float*)(w + 96 * MB);   // 32MB, live to end
    short* y_t   = (short*)(w + 128 * MB);  // 16MB, dead after gemm2
    short* h_t   = (short*)(w);             // 64MB overlay of [0,64MB)
    short* wqb   = (short*)(w + 144 * MB);
    short* wob   = wqb + 196608;
    short* wm1b  = wob + 65536;
    short* wm2b  = wm1b + 262144;

    const size_t SZ = (size_t)B_ * C_ * L_;

    hipMemsetAsync(attnf, 0, SZ * sizeof(float), stream);
    wconv_k<<<384, 256, 0, stream>>>(w_qkv, w_out, w_mlp1, w_mlp2, wqb, wob, wm1b, wm2b);
    prep_k <<<dim3(128, 4, B_), 256, 0, stream>>>(x, pos, xp_t);

    mgemm<0><<<dim3(64, 6, B_), 256, 0, stream>>>(wqb, xp_t, b_qkv, nullptr, qb);
    attn_k  <<<dim3(NWIN, NH, B_), 256, 0, stream>>>(qb, qb + SZ, qb + 2 * SZ, attnf);
    mgemm<1><<<dim3(64, 2, B_), 256, 0, stream>>>(wob, attnf, b_out, x, yb);
    norm_k  <<<B_ * C_, 256, 0, stream>>>(yb, nullptr, yb);
    prep_k <<<dim3(128, 4, B_), 256, 0, stream>>>(yb, nullptr, y_t);
    mgemm<2><<<dim3(64, 8, B_), 256, 0, stream>>>(wm1b, y_t, b_mlp1, nullptr, h_t);
    mgemm<3><<<dim3(64, 2, B_), 256, 0, stream>>>(wm2b, h_t, b_mlp2, nullptr, out);
    norm_k  <<<B_ * C_, 256, 0, stream>>>(out, yb, out);
}

// Round 3
// 242.509 us; speedup vs baseline: 4.5046x; 3.3335x over previous
//
#include <hip/hip_runtime.h>
#include <hip/hip_bf16.h>
#include <math.h>

#define B_   4
#define C_   256
#define L_   8192
#define NH   8
#define HD   32
#define WIN  256
#define STR  192
#define NWIN 43
#define HID  1024

typedef short short8 __attribute__((ext_vector_type(8)));
typedef float f32x4  __attribute__((ext_vector_type(4)));

typedef __attribute__((address_space(3))) unsigned int       as3_u32;
typedef __attribute__((address_space(1))) const unsigned int as1_u32;

__device__ __forceinline__ void gll16(const void* g, void* l) {
    __builtin_amdgcn_global_load_lds((as1_u32*)g, (as3_u32*)l, 16, 0, 0);
}

__device__ __forceinline__ short f2b(float f) {          // f32 -> bf16 RNE
    unsigned u = __builtin_bit_cast(unsigned, f);
    u += 0x7fffu + ((u >> 16) & 1u);
    return (short)(u >> 16);
}
__device__ __forceinline__ float b2f(short s) {
    return __builtin_bit_cast(float, (unsigned)((unsigned short)s) << 16);
}
__device__ __forceinline__ unsigned pk2(float a, float b) {
    return (unsigned)(unsigned short)f2b(a) | ((unsigned)(unsigned short)f2b(b) << 16);
}
__device__ __forceinline__ float gelu_exact(float v) {
    return 0.5f * v * (1.0f + erff(v * 0.70710678118654752f));
}

// ---------------------------------------------------------------------------
// bf16 MFMA GEMM: out[b,o,l] = sum_c W[o,c] * X[b,l,c]   (X stored K-contiguous)
// 128x128 tile, BK=32, 4 waves (2x2), each wave 64x64 = 4x4 frags of 16x16x32.
// MODE 0: qkv  (M=768,K=256)  -> +bias, bf16 q/k/v [part][b][h][l][d]
// MODE 1: proj (M=256,K=256)  -> +bias+resid, f32 y [b][C][l]
// MODE 2: mlp1 (M=1024,K=256) -> gelu(+bias), bf16 h_t [b][l][HID]
// MODE 3: mlp2 (M=256,K=1024) -> +bias, f32 d_out [b][C][l]
// ---------------------------------------------------------------------------
template<int MODE>
__global__ __launch_bounds__(256)
void mgemm(const short* __restrict__ Wb, const short* __restrict__ Xsrc,
           const float* __restrict__ bias, const float* __restrict__ resid,
           void* __restrict__ outp)
{
    constexpr int K = (MODE == 3) ? 1024 : 256;
    constexpr int M = (MODE == 0) ? 768 : (MODE == 2) ? 1024 : 256;
    constexpr int LDSZ = (MODE == 0 || MODE == 2) ? 34816 : 16384;
    __shared__ __align__(16) char lds[LDSZ];

    const int t    = threadIdx.x;
    const int lane = t & 63, wid = t >> 6;
    const int wm   = wid >> 1, wn = wid & 1;
    const int b    = blockIdx.z;
    const int o0   = blockIdx.y * 128;
    const int l0   = blockIdx.x * 128;

    const int l15 = lane & 15, kb = lane >> 4;
    const int swz = kb ^ ((l15 >> 1) & 3);
    const int offA = (wm * 64 + l15) * 64 + swz * 16;
    const int offB = 8192 + (wn * 64 + l15) * 64 + swz * 16;

    f32x4 acc[4][4] = {};

    const short* Xb = Xsrc + (size_t)b * L_ * K;

    for (int c0 = 0; c0 < K; c0 += 32) {
        __syncthreads();
        #pragma unroll
        for (int it = 0; it < 2; ++it) {
            int r = (t >> 2) + it * 64;
            int clog = (t & 3) ^ ((r >> 1) & 3);
            gll16(Wb + (size_t)(o0 + r) * K + c0 + clog * 8,
                  lds + (wid * 64 + it * 256) * 16);
        }
        #pragma unroll
        for (int it = 0; it < 2; ++it) {
            int r = (t >> 2) + it * 64;
            int clog = (t & 3) ^ ((r >> 1) & 3);
            gll16(Xb + (size_t)(l0 + r) * K + c0 + clog * 8,
                  lds + 8192 + (wid * 64 + it * 256) * 16);
        }
        __syncthreads();
        short8 af[4], bf[4];
        #pragma unroll
        for (int i = 0; i < 4; ++i) af[i] = *(const short8*)(lds + offA + i * 1024);
        #pragma unroll
        for (int j = 0; j < 4; ++j) bf[j] = *(const short8*)(lds + offB + j * 1024);
        #pragma unroll
        for (int i = 0; i < 4; ++i)
            #pragma unroll
            for (int j = 0; j < 4; ++j)
                acc[i][j] = __builtin_amdgcn_mfma_f32_16x16x32_bf16(af[i], bf[j], acc[i][j], 0, 0, 0);
    }

    const int orow = (lane >> 4) * 4;

    if constexpr (MODE == 1 || MODE == 3) {
        float* out = (float*)outp;
        #pragma unroll
        for (int i = 0; i < 4; ++i) {
            #pragma unroll
            for (int r = 0; r < 4; ++r) {
                const int o = o0 + wm * 64 + i * 16 + orow + r;
                const float bv = bias[o];
                #pragma unroll
                for (int j = 0; j < 4; ++j) {
                    const int l = l0 + wn * 64 + j * 16 + l15;
                    float v = acc[i][j][r] + bv;
                    if (MODE == 1) v += resid[((size_t)b * C_ + o) * L_ + l];
                    out[((size_t)b * M + o) * L_ + l] = v;
                }
            }
        }
    } else {
        __syncthreads();
        short* Ts = (short*)lds;
        #pragma unroll
        for (int i = 0; i < 4; ++i) {
            #pragma unroll
            for (int r = 0; r < 4; ++r) {
                const int ol = wm * 64 + i * 16 + orow + r;
                const float bv = bias[o0 + ol];
                #pragma unroll
                for (int j = 0; j < 4; ++j) {
                    const int ll = wn * 64 + j * 16 + l15;
                    float v = acc[i][j][r] + bv;
                    if (MODE == 2) v = gelu_exact(v);
                    Ts[ll * 136 + ol] = f2b(v);
                }
            }
        }
        __syncthreads();
        if constexpr (MODE == 2) {
            short* ht = (short*)outp;
            #pragma unroll
            for (int it = 0; it < 8; ++it) {
                int idx = t + it * 256;
                int ll = idx >> 4, ck = (idx & 15) * 8;
                short8 v = *(const short8*)(Ts + ll * 136 + ck);
                *(short8*)(ht + ((size_t)b * L_ + l0 + ll) * HID + o0 + ck) = v;
            }
        } else {
            short* qkv = (short*)outp;
            #pragma unroll
            for (int it = 0; it < 8; ++it) {
                int idx = t + it * 256;
                int hb = idx >> 9, rem = idx & 511;
                int ll = rem >> 2, dk = (rem & 3) * 8;
                short8 v = *(const short8*)(Ts + ll * 136 + hb * 32 + dk);
                int og = o0 + hb * 32;
                int part = og >> 8, h = (og & 255) >> 5;
                short* dst = qkv + (size_t)part * ((size_t)B_ * NH * L_ * HD)
                           + (((size_t)(b * NH + h) * L_ + l0 + ll) * HD + dk);
                *(short8*)dst = v;
            }
        }
    }
}

// ---------------------------------------------------------------------------
// MFMA windowed attention. Block = (window n, head h, batch b), 4 waves.
// Wave w owns query rows start + w*64 .. +63.  K-tiles of 32 keys.
// S^T = mfma(K,Q): lane holds q on col axis -> softmax mostly in-lane.
// P -> wave-private LDS -> PV as O^T = V^T * P^T.  Output: win_out bf16
// [b][h][n][q 256][d 32], no atomics.
// ---------------------------------------------------------------------------
__global__ __launch_bounds__(256)
void attn_k(const short* __restrict__ q, const short* __restrict__ k,
            const short* __restrict__ v, short* __restrict__ win_out)
{
    __shared__ __align__(16) short Kl[256][40];     // [k][d], pad 40
    __shared__ __align__(16) short Vt[32][264];     // [d][k], pad 264
    __shared__ __align__(16) short Pl[4][64][40];   // per-wave [q][k-tile 32], pad 40

    const int n = blockIdx.x, h = blockIdx.y, b = blockIdx.z;
    const int start = n * STR;
    const int t = threadIdx.x;
    const int lane = t & 63, w = t >> 6;
    const int l15 = lane & 15, kb = lane >> 4;
    const size_t hbase = (size_t)(b * NH + h) * L_ * HD;

    // ---- stage K ([k][d]) and V transposed ([d][k]) ----
    {
        int l = start + t; if (l > L_ - 1) l = L_ - 1;
        const short8* gk = (const short8*)&k[hbase + (size_t)l * HD];
        const short8* gv = (const short8*)&v[hbase + (size_t)l * HD];
        short8 k0 = gk[0], k1 = gk[1], k2 = gk[2], k3 = gk[3];
        short8 v0 = gv[0], v1 = gv[1], v2 = gv[2], v3 = gv[3];
        *(short8*)&Kl[t][0]  = k0; *(short8*)&Kl[t][8]  = k1;
        *(short8*)&Kl[t][16] = k2; *(short8*)&Kl[t][24] = k3;
        #pragma unroll
        for (int e = 0; e < 8; ++e) {
            Vt[e][t]      = v0[e];
            Vt[8 + e][t]  = v1[e];
            Vt[16 + e][t] = v2[e];
            Vt[24 + e][t] = v3[e];
        }
    }

    // ---- Q fragments from global (B-operand: lane holds Q[q=l15+16j][d=kb*8..+7]) ----
    short8 qf[4];
    #pragma unroll
    for (int j = 0; j < 4; ++j) {
        int lq = start + w * 64 + j * 16 + l15; if (lq > L_ - 1) lq = L_ - 1;
        qf[j] = *(const short8*)&q[hbase + (size_t)lq * HD + kb * 8];
    }
    __syncthreads();

    const float SCALE = 0.17677669529663687f;   // 1/sqrt(32)
    const bool domask = (start + WIN > L_);

    f32x4 ot[2][4] = {};
    float m[4]  = {-INFINITY, -INFINITY, -INFINITY, -INFINITY};
    float ls[4] = {};
    const f32x4 zacc = {};

    for (int kt = 0; kt < 8; ++kt) {
        // QK^T (swapped): S^T rows = k, cols = q
        short8 ka[2];
        #pragma unroll
        for (int i = 0; i < 2; ++i)
            ka[i] = *(const short8*)&Kl[kt * 32 + i * 16 + l15][kb * 8];
        f32x4 st[2][4];
        #pragma unroll
        for (int i = 0; i < 2; ++i)
            #pragma unroll
            for (int j = 0; j < 4; ++j)
                st[i][j] = __builtin_amdgcn_mfma_f32_16x16x32_bf16(ka[i], qf[j], zacc, 0, 0, 0);

        if (domask) {
            #pragma unroll
            for (int i = 0; i < 2; ++i)
                #pragma unroll
                for (int r = 0; r < 4; ++r) {
                    int kp = start + kt * 32 + i * 16 + kb * 4 + r;
                    if (kp >= L_) {
                        #pragma unroll
                        for (int j = 0; j < 4; ++j) st[i][j][r] = -1e30f;
                    }
                }
        }

        // online softmax per q-col (j-th fragment, col = j*16+l15)
        #pragma unroll
        for (int j = 0; j < 4; ++j) {
            float tm = -1e30f;
            #pragma unroll
            for (int i = 0; i < 2; ++i)
                #pragma unroll
                for (int r = 0; r < 4; ++r) tm = fmaxf(tm, st[i][j][r]);
            tm = fmaxf(tm, __shfl_xor(tm, 16));
            tm = fmaxf(tm, __shfl_xor(tm, 32));
            float mn = fmaxf(m[j], tm);
            float al = __expf((m[j] - mn) * SCALE);
            m[j] = mn;
            float rs = 0.f;
            #pragma unroll
            for (int i = 0; i < 2; ++i)
                #pragma unroll
                for (int r = 0; r < 4; ++r) {
                    float p = __expf((st[i][j][r] - mn) * SCALE);
                    st[i][j][r] = p;
                    rs += p;
                }
            rs += __shfl_xor(rs, 16);
            rs += __shfl_xor(rs, 32);
            ls[j] = ls[j] * al + rs;
            ot[0][j] *= al;
            ot[1][j] *= al;
        }

        // write P (bf16) to wave-private LDS: P[q][k_local]
        #pragma unroll
        for (int i = 0; i < 2; ++i)
            #pragma unroll
            for (int j = 0; j < 4; ++j) {
                uint2 u;
                u.x = pk2(st[i][j][0], st[i][j][1]);
                u.y = pk2(st[i][j][2], st[i][j][3]);
                *(uint2*)&Pl[w][j * 16 + l15][i * 16 + kb * 4] = u;
            }
        asm volatile("s_waitcnt lgkmcnt(0)" ::: "memory");
        __builtin_amdgcn_sched_barrier(0);

        // PV: O^T += V^T * P^T
        short8 pb[4], va[2];
        #pragma unroll
        for (int j = 0; j < 4; ++j)
            pb[j] = *(const short8*)&Pl[w][j * 16 + l15][kb * 8];
        #pragma unroll
        for (int i = 0; i < 2; ++i)
            va[i] = *(const short8*)&Vt[i * 16 + l15][kt * 32 + kb * 8];
        #pragma unroll
        for (int i = 0; i < 2; ++i)
            #pragma unroll
            for (int j = 0; j < 4; ++j)
                ot[i][j] = __builtin_amdgcn_mfma_f32_16x16x32_bf16(va[i], pb[j], ot[i][j], 0, 0, 0);
    }

    // ---- epilogue: scale by 1/lsum, write win_out[b][h][n][q][d] bf16 ----
    float inv[4];
    #pragma unroll
    for (int j = 0; j < 4; ++j) inv[j] = 1.0f / ls[j];
    short* base = win_out + (((size_t)(b * NH + h) * NWIN + n) * WIN) * HD;
    #pragma unroll
    for (int i = 0; i < 2; ++i)
        #pragma unroll
        for (int j = 0; j < 4; ++j) {
            int qrow = w * 64 + j * 16 + l15;
            int d    = i * 16 + kb * 4;
            f32x4 o = ot[i][j];
            uint2 u;
            u.x = pk2(o[0] * inv[j], o[1] * inv[j]);
            u.y = pk2(o[2] * inv[j], o[3] * inv[j]);
            *(uint2*)&base[(size_t)qrow * HD + d] = u;
        }
}

// ---------------------------------------------------------------------------
// Combine overlapping windows: attn_t[b][l][c] = (sum of 1-2 windows)/cnt, bf16.
// Thread handles one (l, h). No atomics, no memset.
// ---------------------------------------------------------------------------
__global__ __launch_bounds__(256)
void comb_k(const short* __restrict__ win, short* __restrict__ attn_t)
{
    const int t = threadIdx.x, b = blockIdx.y;
    const int l = blockIdx.x * 32 + (t >> 3), h = t & 7;
    const int n1 = l / STR, j1 = l - n1 * STR;
    const bool two = (n1 >= 1) && (j1 < WIN - STR);

    const short8* p1 = (const short8*)&win[((((size_t)b * NH + h) * NWIN + n1) * WIN + j1) * HD];
    float f[32];
    #pragma unroll
    for (int c = 0; c < 4; ++c) {
        short8 a = p1[c];
        #pragma unroll
        for (int e = 0; e < 8; ++e) f[c * 8 + e] = b2f(a[e]);
    }
    if (two) {
        const short8* p0 = (const short8*)&win[((((size_t)b * NH + h) * NWIN + n1 - 1) * WIN + j1 + STR) * HD];
        #pragma unroll
        for (int c = 0; c < 4; ++c) {
            short8 a = p0[c];
            #pragma unroll
            for (int e = 0; e < 8; ++e) f[c * 8 + e] = (f[c * 8 + e] + b2f(a[e])) * 0.5f;
        }
    }
    short8* dst = (short8*)&attn_t[((size_t)b * L_ + l) * C_ + h * HD];
    #pragma unroll
    for (int c = 0; c < 4; ++c) {
        short8 o;
        #pragma unroll
        for (int e = 0; e < 8; ++e) o[e] = f2b(f[c * 8 + e]);
        dst[c] = o;
    }
}

// ---------------------------------------------------------------------------
// Transpose+convert: f32 [B][C][L] (+optional pos[c]) -> bf16 [B][L][C]
// ---------------------------------------------------------------------------
__global__ __launch_bounds__(256)
void prep_k(const float* __restrict__ in, const float* __restrict__ pos,
            short* __restrict__ outT)
{
    __shared__ float T[64][65];
    const int b = blockIdx.z, c0 = blockIdx.y * 64, l0 = blockIdx.x * 64;
    const int t = threadIdx.x;
    #pragma unroll
    for (int it = 0; it < 4; ++it) {
        int idx = t + it * 256;
        int c = idx >> 4, l4 = (idx & 15) * 4;
        float4 v = *(const float4*)&in[((size_t)b * C_ + c0 + c) * L_ + l0 + l4];
        float p = pos ? pos[c0 + c] : 0.f;
        T[c][l4 + 0] = v.x + p; T[c][l4 + 1] = v.y + p;
        T[c][l4 + 2] = v.z + p; T[c][l4 + 3] = v.w + p;
    }
    __syncthreads();
    #pragma unroll
    for (int it = 0; it < 2; ++it) {
        int idx = t + it * 256;
        int l = idx >> 3, ck = (idx & 7) * 8;
        short8 o;
        #pragma unroll
        for (int j = 0; j < 8; ++j) o[j] = f2b(T[ck + j][l]);
        *(short8*)&outT[((size_t)b * L_ + l0 + l) * C_ + c0 + ck] = o;
    }
}

__global__ __launch_bounds__(256)
void wconv_k(const float* a, const float* b, const float* c, const float* d,
             short* oa, short* ob, short* oc, short* od)
{
    int i = (blockIdx.x * 256 + threadIdx.x) * 8;
    const float* s; short* o; int off;
    if (i < 196608)      { s = a; o = oa; off = i; }
    else if (i < 262144) { s = b; o = ob; off = i - 196608; }
    else if (i < 524288) { s = c; o = oc; off = i - 262144; }
    else                 { s = d; o = od; off = i - 524288; }
    float4 v0 = *(const float4*)(s + off);
    float4 v1 = *(const float4*)(s + off + 4);
    short8 r;
    r[0] = f2b(v0.x); r[1] = f2b(v0.y); r[2] = f2b(v0.z); r[3] = f2b(v0.w);
    r[4] = f2b(v1.x); r[5] = f2b(v1.y); r[6] = f2b(v1.z); r[7] = f2b(v1.w);
    *(short8*)(o + off) = r;
}

__global__ __launch_bounds__(256)
void norm_k(const float* __restrict__ src, const float* __restrict__ add,
            float* __restrict__ dst)
{
    const int row = blockIdx.x;
    const float* s = src + (size_t)row * L_;
    const int t = threadIdx.x;
    float4 vals[8];
    float sum = 0.f, ssq = 0.f;
    #pragma unroll
    for (int i = 0; i < 8; ++i) {
        float4 vv = *(const float4*)&s[t * 4 + i * 1024];
        vals[i] = vv;
        sum += (vv.x + vv.y) + (vv.z + vv.w);
        ssq += vv.x*vv.x + vv.y*vv.y + vv.z*vv.z + vv.w*vv.w;
    }
    #pragma unroll
    for (int off = 32; off > 0; off >>= 1) {
        sum += __shfl_down(sum, off);
        ssq += __shfl_down(ssq, off);
    }
    __shared__ float rbuf[8];
    __shared__ float s_mean, s_rstd;
    if ((t & 63) == 0) { rbuf[t >> 6] = sum; rbuf[4 + (t >> 6)] = ssq; }
    __syncthreads();
    if (t == 0) {
        float a  = (rbuf[0] + rbuf[1]) + (rbuf[2] + rbuf[3]);
        float q2 = (rbuf[4] + rbuf[5]) + (rbuf[6] + rbuf[7]);
        float mean = a * (1.0f / L_);
        float var  = q2 * (1.0f / L_) - mean * mean;
        s_mean = mean;
        s_rstd = rsqrtf(var + 1e-5f);
    }
    __syncthreads();
    const float mean = s_mean, rstd = s_rstd;
    float* d = dst + (size_t)row * L_;
    const float* ar = add ? add + (size_t)row * L_ : nullptr;
    #pragma unroll
    for (int i = 0; i < 8; ++i) {
        float4 vv = vals[i];
        vv.x = (vv.x - mean) * rstd;
        vv.y = (vv.y - mean) * rstd;
        vv.z = (vv.z - mean) * rstd;
        vv.w = (vv.w - mean) * rstd;
        if (ar) {
            float4 av = *(const float4*)&ar[t * 4 + i * 1024];
            vv.x += av.x; vv.y += av.y; vv.z += av.z; vv.w += av.w;
        }
        *(float4*)&d[t * 4 + i * 1024] = vv;
    }
}

extern "C" void kernel_launch(void* const* d_in, const int* in_sizes, int n_in,
                              void* d_out, int out_size, void* d_ws, size_t ws_size,
                              hipStream_t stream) {
    const float* x      = (const float*)d_in[0];
    const float* pos    = (const float*)d_in[1];
    const float* w_qkv  = (const float*)d_in[2];
    const float* b_qkv  = (const float*)d_in[3];
    const float* w_out  = (const float*)d_in[4];
    const float* b_out  = (const float*)d_in[5];
    const float* w_mlp1 = (const float*)d_in[6];
    const float* b_mlp1 = (const float*)d_in[7];
    const float* w_mlp2 = (const float*)d_in[8];
    const float* b_mlp2 = (const float*)d_in[9];
    float* out = (float*)d_out;

    constexpr size_t MB = 1u << 20;
    char* w = (char*)d_ws;
    short* xp_t  = (short*)(w);              // 16MB, dead after mgemm<0>
    short* qb    = (short*)(w + 16 * MB);    // 48MB q/k/v, dead after attn_k
    short* winb  = (short*)(w + 64 * MB);    // 21.5MB win_out
    short* at_t  = (short*)(w + 88 * MB);    // 16MB attn_t
    float* yb    = (float*)(w + 104 * MB);   // 32MB f32 y
    short* y_t   = (short*)(w + 136 * MB);   // 16MB
    short* h_t   = (short*)(w);              // 64MB overlay [0,64)
    short* wqb   = (short*)(w + 152 * MB);
    short* wob   = wqb + 196608;
    short* wm1b  = wob + 65536;
    short* wm2b  = wm1b + 262144;

    const size_t SZ = (size_t)B_ * C_ * L_;

    wconv_k<<<384, 256, 0, stream>>>(w_qkv, w_out, w_mlp1, w_mlp2, wqb, wob, wm1b, wm2b);
    prep_k <<<dim3(128, 4, B_), 256, 0, stream>>>(x, pos, xp_t);

    mgemm<0><<<dim3(64, 6, B_), 256, 0, stream>>>(wqb, xp_t, b_qkv, nullptr, qb);
    attn_k  <<<dim3(NWIN, NH, B_), 256, 0, stream>>>(qb, qb + SZ, qb + 2 * SZ, winb);
    comb_k  <<<dim3(L_ / 32, B_), 256, 0, stream>>>(winb, at_t);
    mgemm<1><<<dim3(64, 2, B_), 256, 0, stream>>>(wob, at_t, b_out, x, yb);
    norm_k  <<<B_ * C_, 256, 0, stream>>>(yb, nullptr, yb);
    prep_k <<<dim3(128, 4, B_), 256, 0, stream>>>(yb, nullptr, y_t);
    mgemm<2><<<dim3(64, 8, B_), 256, 0, stream>>>(wm1b, y_t, b_mlp1, nullptr, h_t);
    mgemm<3><<<dim3(64, 2, B_), 256, 0, stream>>>(wm2b, h_t, b_mlp2, nullptr, out);
    norm_k  <<<B_ * C_, 256, 0, stream>>>(out, yb, out);
}

// Round 4
// 205.328 us; speedup vs baseline: 5.3202x; 1.1811x over previous
//
#include <hip/hip_runtime.h>
#include <hip/hip_bf16.h>
#include <math.h>

#define B_   4
#define C_   256
#define L_   8192
#define NH   8
#define HD   32
#define WIN  256
#define STR  192
#define NWIN 43
#define HID  1024

typedef short short8 __attribute__((ext_vector_type(8)));
typedef float f32x4  __attribute__((ext_vector_type(4)));

typedef __attribute__((address_space(3))) unsigned int       as3_u32;
typedef __attribute__((address_space(1))) const unsigned int as1_u32;

__device__ __forceinline__ void gll16(const void* g, void* l) {
    __builtin_amdgcn_global_load_lds((as1_u32*)g, (as3_u32*)l, 16, 0, 0);
}

__device__ __forceinline__ short f2b(float f) {          // f32 -> bf16 RNE
    unsigned u = __builtin_bit_cast(unsigned, f);
    u += 0x7fffu + ((u >> 16) & 1u);
    return (short)(u >> 16);
}
__device__ __forceinline__ float b2f(short s) {
    return __builtin_bit_cast(float, (unsigned)((unsigned short)s) << 16);
}
__device__ __forceinline__ unsigned pk2(float a, float b) {
    return (unsigned)(unsigned short)f2b(a) | ((unsigned)(unsigned short)f2b(b) << 16);
}
__device__ __forceinline__ float gelu_exact(float v) {
    return 0.5f * v * (1.0f + erff(v * 0.70710678118654752f));
}

// ---------------------------------------------------------------------------
// bf16 MFMA GEMM, 128x128 tile, BK=64 (2 kk sub-steps of K=32), 4 waves.
// LDS: A[128 rows][8 chunks of 16B], chunk-swizzled phys = logical ^ (row&7),
// achieved by pre-swizzling the global source; dest stays linear for
// global_load_lds.  Frag reads are conflict-free (8 distinct chunks / 8 lanes).
// MODE 0: qkv  (M=768,K=256)  -> +bias (q rows pre-scaled 1/sqrt(32)),
//                                bf16 q/k/v [part][b][h][l][d]
// MODE 1: proj (M=256,K=256)  B = window-combine of win_out (fused comb_k)
//                             -> +bias+resid, f32 y [b][C][l]
// MODE 2: mlp1 (M=1024,K=256) -> gelu(+bias), bf16 h_t [b][l][HID]
// MODE 3: mlp2 (M=256,K=1024) -> +bias, f32 d_out [b][C][l]
// ---------------------------------------------------------------------------
template<int MODE>
__global__ __launch_bounds__(256)
void mgemm(const short* __restrict__ Wb, const short* __restrict__ Xsrc,
           const float* __restrict__ bias, const float* __restrict__ resid,
           void* __restrict__ outp)
{
    constexpr int K = (MODE == 3) ? 1024 : 256;
    constexpr int M = (MODE == 0) ? 768 : (MODE == 2) ? 1024 : 256;
    constexpr int LDSZ = (MODE == 0 || MODE == 2) ? 34816 : 32768;
    __shared__ __align__(16) char lds[LDSZ];

    const int t    = threadIdx.x;
    const int lane = t & 63, wid = t >> 6;
    const int wm   = wid >> 1, wn = wid & 1;
    const int b    = blockIdx.z;
    const int o0   = blockIdx.y * 128;
    const int l0   = blockIdx.x * 128;
    const int l15  = lane & 15, kb = lane >> 4;

    f32x4 acc[4][4] = {};
    const short* Xb = Xsrc + (size_t)b * L_ * K;

    // MODE 1: per-staged-row window indices (independent of k)
    int pn1[4], pj1[4]; bool ptwo[4];
    if constexpr (MODE == 1) {
        #pragma unroll
        for (int it = 0; it < 4; ++it) {
            int r = (it * 256 + t) >> 3;
            int l = l0 + r;
            int n1 = l / STR;
            pn1[it] = n1; pj1[it] = l - n1 * STR;
            ptwo[it] = (n1 >= 1) && (pj1[it] < WIN - STR);
        }
    }

    for (int c0 = 0; c0 < K; c0 += 64) {
        __syncthreads();
        // ---- stage A (weights) ----
        #pragma unroll
        for (int it = 0; it < 4; ++it) {
            int d = it * 256 + t;
            int r = d >> 3, pc = d & 7;
            int clog = pc ^ (r & 7);
            gll16(Wb + (size_t)(o0 + r) * K + c0 + clog * 8,
                  lds + (it * 256 + wid * 64) * 16);
        }
        // ---- stage B ----
        if constexpr (MODE == 1) {
            #pragma unroll
            for (int it = 0; it < 4; ++it) {
                int d = it * 256 + t;
                int r = d >> 3, pc = d & 7;
                int clog = pc ^ (r & 7);
                int c = c0 + clog * 8;
                int h = c >> 5, dd = c & 31;
                size_t base = ((((size_t)(b * NH + h)) * NWIN + pn1[it]) * WIN + pj1[it]) * HD + dd;
                short8 vv = *(const short8*)&Xsrc[base];
                if (ptwo[it]) {
                    short8 u = *(const short8*)&Xsrc[base - 2048];  // (n1-1, j1+192)
                    #pragma unroll
                    for (int e = 0; e < 8; ++e) vv[e] = f2b(b2f(vv[e]) + b2f(u[e]));
                }
                *(short8*)(lds + 16384 + d * 16) = vv;
            }
        } else {
            #pragma unroll
            for (int it = 0; it < 4; ++it) {
                int d = it * 256 + t;
                int r = d >> 3, pc = d & 7;
                int clog = pc ^ (r & 7);
                gll16(Xb + (size_t)(l0 + r) * K + c0 + clog * 8,
                      lds + 16384 + (it * 256 + wid * 64) * 16);
            }
        }
        __syncthreads();
        // ---- compute: 2 kk sub-steps of 16 MFMA ----
        #pragma unroll
        for (int kk = 0; kk < 2; ++kk) {
            short8 af[4], bf[4];
            #pragma unroll
            for (int i = 0; i < 4; ++i)
                af[i] = *(const short8*)(lds +
                    ((wm * 64 + i * 16 + l15) * 8 + ((kk * 4 + kb) ^ (l15 & 7))) * 16);
            #pragma unroll
            for (int j = 0; j < 4; ++j)
                bf[j] = *(const short8*)(lds + 16384 +
                    ((wn * 64 + j * 16 + l15) * 8 + ((kk * 4 + kb) ^ (l15 & 7))) * 16);
            #pragma unroll
            for (int i = 0; i < 4; ++i)
                #pragma unroll
                for (int j = 0; j < 4; ++j)
                    acc[i][j] = __builtin_amdgcn_mfma_f32_16x16x32_bf16(af[i], bf[j], acc[i][j], 0, 0, 0);
        }
    }

    const int orow = (lane >> 4) * 4;

    if constexpr (MODE == 1 || MODE == 3) {
        float* out = (float*)outp;
        #pragma unroll
        for (int i = 0; i < 4; ++i) {
            #pragma unroll
            for (int r = 0; r < 4; ++r) {
                const int o = o0 + wm * 64 + i * 16 + orow + r;
                const float bv = bias[o];
                #pragma unroll
                for (int j = 0; j < 4; ++j) {
                    const int l = l0 + wn * 64 + j * 16 + l15;
                    float v = acc[i][j][r] + bv;
                    if (MODE == 1) v += resid[((size_t)b * C_ + o) * L_ + l];
                    out[((size_t)b * M + o) * L_ + l] = v;
                }
            }
        }
    } else {
        __syncthreads();
        short* Ts = (short*)lds;
        const float qscale = (MODE == 0 && o0 < 256) ? 0.17677669529663687f : 1.0f;
        #pragma unroll
        for (int i = 0; i < 4; ++i) {
            #pragma unroll
            for (int r = 0; r < 4; ++r) {
                const int ol = wm * 64 + i * 16 + orow + r;
                const float bv = bias[o0 + ol];
                #pragma unroll
                for (int j = 0; j < 4; ++j) {
                    const int ll = wn * 64 + j * 16 + l15;
                    float v = acc[i][j][r] + bv;
                    if (MODE == 2) v = gelu_exact(v);
                    if (MODE == 0) v *= qscale;
                    Ts[ll * 136 + ol] = f2b(v);
                }
            }
        }
        __syncthreads();
        if constexpr (MODE == 2) {
            short* ht = (short*)outp;
            #pragma unroll
            for (int it = 0; it < 8; ++it) {
                int idx = t + it * 256;
                int ll = idx >> 4, ck = (idx & 15) * 8;
                short8 v = *(const short8*)(Ts + ll * 136 + ck);
                *(short8*)(ht + ((size_t)b * L_ + l0 + ll) * HID + o0 + ck) = v;
            }
        } else {
            short* qkv = (short*)outp;
            #pragma unroll
            for (int it = 0; it < 8; ++it) {
                int idx = t + it * 256;
                int hb = idx >> 9, rem = idx & 511;
                int ll = rem >> 2, dk = (rem & 3) * 8;
                short8 v = *(const short8*)(Ts + ll * 136 + hb * 32 + dk);
                int og = o0 + hb * 32;
                int part = og >> 8, h = (og & 255) >> 5;
                short* dst = qkv + (size_t)part * ((size_t)B_ * NH * L_ * HD)
                           + (((size_t)(b * NH + h) * L_ + l0 + ll) * HD + dk);
                *(short8*)dst = v;
            }
        }
    }
}

// ---------------------------------------------------------------------------
// MFMA windowed attention, no-max softmax (Q pre-scaled; scores bounded).
// Block = (window, head, batch), 4 waves; wave owns 64 q rows.
// Per k-tile (32): S^T = mfma(K,Q) -> p = exp(s) -> P to wave-private LDS ->
// O^T += V^T P^T.  lsum: per-lane partials, 2 shuffles at the end.
// Epilogue folds 1/lsum AND 1/window-count -> win_out needs only summing.
// ---------------------------------------------------------------------------
__global__ __launch_bounds__(256)
void attn_k(const short* __restrict__ q, const short* __restrict__ k,
            const short* __restrict__ v, short* __restrict__ win_out)
{
    __shared__ __align__(16) short Kl[256][40];
    __shared__ __align__(16) short Vt[32][264];
    __shared__ __align__(16) short Pl[4][64][40];

    const int n = blockIdx.x, h = blockIdx.y, b = blockIdx.z;
    const int start = n * STR;
    const int t = threadIdx.x;
    const int lane = t & 63, w = t >> 6;
    const int l15 = lane & 15, kb = lane >> 4;
    const size_t hbase = (size_t)(b * NH + h) * L_ * HD;

    {
        int l = start + t; if (l > L_ - 1) l = L_ - 1;
        const short8* gk = (const short8*)&k[hbase + (size_t)l * HD];
        const short8* gv = (const short8*)&v[hbase + (size_t)l * HD];
        short8 k0 = gk[0], k1 = gk[1], k2 = gk[2], k3 = gk[3];
        short8 v0 = gv[0], v1 = gv[1], v2 = gv[2], v3 = gv[3];
        *(short8*)&Kl[t][0]  = k0; *(short8*)&Kl[t][8]  = k1;
        *(short8*)&Kl[t][16] = k2; *(short8*)&Kl[t][24] = k3;
        #pragma unroll
        for (int e = 0; e < 8; ++e) {
            Vt[e][t]      = v0[e];
            Vt[8 + e][t]  = v1[e];
            Vt[16 + e][t] = v2[e];
            Vt[24 + e][t] = v3[e];
        }
    }

    short8 qf[4];
    #pragma unroll
    for (int j = 0; j < 4; ++j) {
        int lq = start + w * 64 + j * 16 + l15; if (lq > L_ - 1) lq = L_ - 1;
        qf[j] = *(const short8*)&q[hbase + (size_t)lq * HD + kb * 8];
    }
    __syncthreads();

    const bool domask = (start + WIN > L_);
    f32x4 ot[2][4] = {};
    float ls[4] = {};
    const f32x4 zacc = {};

    for (int kt = 0; kt < 8; ++kt) {
        short8 ka[2];
        #pragma unroll
        for (int i = 0; i < 2; ++i)
            ka[i] = *(const short8*)&Kl[kt * 32 + i * 16 + l15][kb * 8];
        f32x4 st[2][4];
        #pragma unroll
        for (int i = 0; i < 2; ++i)
            #pragma unroll
            for (int j = 0; j < 4; ++j)
                st[i][j] = __builtin_amdgcn_mfma_f32_16x16x32_bf16(ka[i], qf[j], zacc, 0, 0, 0);

        if (domask) {
            #pragma unroll
            for (int i = 0; i < 2; ++i)
                #pragma unroll
                for (int r = 0; r < 4; ++r) {
                    int kp = start + kt * 32 + i * 16 + kb * 4 + r;
                    if (kp >= L_) {
                        #pragma unroll
                        for (int j = 0; j < 4; ++j) st[i][j][r] = -1e30f;
                    }
                }
        }

        #pragma unroll
        for (int j = 0; j < 4; ++j) {
            #pragma unroll
            for (int i = 0; i < 2; ++i) {
                float p0 = __expf(st[i][j][0]);
                float p1 = __expf(st[i][j][1]);
                float p2 = __expf(st[i][j][2]);
                float p3 = __expf(st[i][j][3]);
                ls[j] += (p0 + p1) + (p2 + p3);
                uint2 u;
                u.x = pk2(p0, p1);
                u.y = pk2(p2, p3);
                *(uint2*)&Pl[w][j * 16 + l15][i * 16 + kb * 4] = u;
            }
        }
        asm volatile("s_waitcnt lgkmcnt(0)" ::: "memory");
        __builtin_amdgcn_sched_barrier(0);

        short8 pb[4], va[2];
        #pragma unroll
        for (int j = 0; j < 4; ++j)
            pb[j] = *(const short8*)&Pl[w][j * 16 + l15][kb * 8];
        #pragma unroll
        for (int i = 0; i < 2; ++i)
            va[i] = *(const short8*)&Vt[i * 16 + l15][kt * 32 + kb * 8];
        #pragma unroll
        for (int i = 0; i < 2; ++i)
            #pragma unroll
            for (int j = 0; j < 4; ++j)
                ot[i][j] = __builtin_amdgcn_mfma_f32_16x16x32_bf16(va[i], pb[j], ot[i][j], 0, 0, 0);
    }

    // 1/lsum and 1/count folded together
    float sc[4];
    #pragma unroll
    for (int j = 0; j < 4; ++j) {
        float s = ls[j];
        s += __shfl_xor(s, 16);
        s += __shfl_xor(s, 32);
        int lq = start + w * 64 + j * 16 + l15;
        int nhi = lq / STR;
        int nlo = (lq >= WIN) ? ((lq - WIN) / STR + 1) : 0;
        sc[j] = 1.0f / (s * (float)(nhi - nlo + 1));
    }

    short* base = win_out + (((size_t)(b * NH + h) * NWIN + n) * WIN) * HD;
    #pragma unroll
    for (int i = 0; i < 2; ++i)
        #pragma unroll
        for (int j = 0; j < 4; ++j) {
            int qrow = w * 64 + j * 16 + l15;
            int d    = i * 16 + kb * 4;
            f32x4 o = ot[i][j];
            uint2 u;
            u.x = pk2(o[0] * sc[j], o[1] * sc[j]);
            u.y = pk2(o[2] * sc[j], o[3] * sc[j]);
            *(uint2*)&base[(size_t)qrow * HD + d] = u;
        }
}

// ---------------------------------------------------------------------------
// Per-row (b,c) mean/rstd of f32 [B][C][L] -> float2 stats
// ---------------------------------------------------------------------------
__global__ __launch_bounds__(256)
void stats_k(const float* __restrict__ src, float2* __restrict__ stt)
{
    const int row = blockIdx.x;
    const float* s = src + (size_t)row * L_;
    const int t = threadIdx.x;
    float sum = 0.f, ssq = 0.f;
    #pragma unroll
    for (int i = 0; i < 8; ++i) {
        float4 vv = *(const float4*)&s[t * 4 + i * 1024];
        sum += (vv.x + vv.y) + (vv.z + vv.w);
        ssq += vv.x*vv.x + vv.y*vv.y + vv.z*vv.z + vv.w*vv.w;
    }
    #pragma unroll
    for (int off = 32; off > 0; off >>= 1) {
        sum += __shfl_down(sum, off);
        ssq += __shfl_down(ssq, off);
    }
    __shared__ float rbuf[8];
    if ((t & 63) == 0) { rbuf[t >> 6] = sum; rbuf[4 + (t >> 6)] = ssq; }
    __syncthreads();
    if (t == 0) {
        float a  = (rbuf[0] + rbuf[1]) + (rbuf[2] + rbuf[3]);
        float q2 = (rbuf[4] + rbuf[5]) + (rbuf[6] + rbuf[7]);
        float mean = a * (1.0f / L_);
        float var  = q2 * (1.0f / L_) - mean * mean;
        stt[row] = make_float2(mean, rsqrtf(var + 1e-5f));
    }
}

// ---------------------------------------------------------------------------
// Transpose+convert: f32 [B][C][L] -> bf16 [B][L][C], optional +pos[c],
// optional per-row instance-norm via stats.
// ---------------------------------------------------------------------------
__global__ __launch_bounds__(256)
void prep_k(const float* __restrict__ in, const float* __restrict__ pos,
            const float2* __restrict__ stt, short* __restrict__ outT)
{
    __shared__ float T[64][65];
    const int b = blockIdx.z, c0 = blockIdx.y * 64, l0 = blockIdx.x * 64;
    const int t = threadIdx.x;
    #pragma unroll
    for (int it = 0; it < 4; ++it) {
        int idx = t + it * 256;
        int c = idx >> 4, l4 = (idx & 15) * 4;
        float4 v = *(const float4*)&in[((size_t)b * C_ + c0 + c) * L_ + l0 + l4];
        if (stt) {
            float2 ms = stt[b * C_ + c0 + c];
            v.x = (v.x - ms.x) * ms.y; v.y = (v.y - ms.x) * ms.y;
            v.z = (v.z - ms.x) * ms.y; v.w = (v.w - ms.x) * ms.y;
        }
        float p = pos ? pos[c0 + c] : 0.f;
        T[c][l4 + 0] = v.x + p; T[c][l4 + 1] = v.y + p;
        T[c][l4 + 2] = v.z + p; T[c][l4 + 3] = v.w + p;
    }
    __syncthreads();
    #pragma unroll
    for (int it = 0; it < 2; ++it) {
        int idx = t + it * 256;
        int l = idx >> 3, ck = (idx & 7) * 8;
        short8 o;
        #pragma unroll
        for (int j = 0; j < 8; ++j) o[j] = f2b(T[ck + j][l]);
        *(short8*)&outT[((size_t)b * L_ + l0 + l) * C_ + c0 + ck] = o;
    }
}

__global__ __launch_bounds__(256)
void wconv_k(const float* a, const float* b, const float* c, const float* d,
             short* oa, short* ob, short* oc, short* od)
{
    int i = (blockIdx.x * 256 + threadIdx.x) * 8;
    const float* s; short* o; int off;
    if (i < 196608)      { s = a; o = oa; off = i; }
    else if (i < 262144) { s = b; o = ob; off = i - 196608; }
    else if (i < 524288) { s = c; o = oc; off = i - 262144; }
    else                 { s = d; o = od; off = i - 524288; }
    float4 v0 = *(const float4*)(s + off);
    float4 v1 = *(const float4*)(s + off + 4);
    short8 r;
    r[0] = f2b(v0.x); r[1] = f2b(v0.y); r[2] = f2b(v0.z); r[3] = f2b(v0.w);
    r[4] = f2b(v1.x); r[5] = f2b(v1.y); r[6] = f2b(v1.z); r[7] = f2b(v1.w);
    *(short8*)(o + off) = r;
}

// ---------------------------------------------------------------------------
// Final: dst = instance_norm(src) + (add_raw - mean)*rstd   (stats from buf)
// ---------------------------------------------------------------------------
__global__ __launch_bounds__(256)
void norm_k(const float* __restrict__ src, const float* __restrict__ add,
            const float2* __restrict__ ast, float* __restrict__ dst)
{
    const int row = blockIdx.x;
    const float* s = src + (size_t)row * L_;
    const int t = threadIdx.x;
    float4 vals[8];
    float sum = 0.f, ssq = 0.f;
    #pragma unroll
    for (int i = 0; i < 8; ++i) {
        float4 vv = *(const float4*)&s[t * 4 + i * 1024];
        vals[i] = vv;
        sum += (vv.x + vv.y) + (vv.z + vv.w);
        ssq += vv.x*vv.x + vv.y*vv.y + vv.z*vv.z + vv.w*vv.w;
    }
    #pragma unroll
    for (int off = 32; off > 0; off >>= 1) {
        sum += __shfl_down(sum, off);
        ssq += __shfl_down(ssq, off);
    }
    __shared__ float rbuf[8];
    __shared__ float s_mean, s_rstd;
    if ((t & 63) == 0) { rbuf[t >> 6] = sum; rbuf[4 + (t >> 6)] = ssq; }
    __syncthreads();
    if (t == 0) {
        float a  = (rbuf[0] + rbuf[1]) + (rbuf[2] + rbuf[3]);
        float q2 = (rbuf[4] + rbuf[5]) + (rbuf[6] + rbuf[7]);
        float mean = a * (1.0f / L_);
        float var  = q2 * (1.0f / L_) - mean * mean;
        s_mean = mean;
        s_rstd = rsqrtf(var + 1e-5f);
    }
    __syncthreads();
    const float mean = s_mean, rstd = s_rstd;
    const float2 ms = ast[row];
    float* d = dst + (size_t)row * L_;
    const float* ar = add + (size_t)row * L_;
    #pragma unroll
    for (int i = 0; i < 8; ++i) {
        float4 vv = vals[i];
        float4 av = *(const float4*)&ar[t * 4 + i * 1024];
        vv.x = (vv.x - mean) * rstd + (av.x - ms.x) * ms.y;
        vv.y = (vv.y - mean) * rstd + (av.y - ms.x) * ms.y;
        vv.z = (vv.z - mean) * rstd + (av.z - ms.x) * ms.y;
        vv.w = (vv.w - mean) * rstd + (av.w - ms.x) * ms.y;
        *(float4*)&d[t * 4 + i * 1024] = vv;
    }
}

extern "C" void kernel_launch(void* const* d_in, const int* in_sizes, int n_in,
                              void* d_out, int out_size, void* d_ws, size_t ws_size,
                              hipStream_t stream) {
    const float* x      = (const float*)d_in[0];
    const float* pos    = (const float*)d_in[1];
    const float* w_qkv  = (const float*)d_in[2];
    const float* b_qkv  = (const float*)d_in[3];
    const float* w_out  = (const float*)d_in[4];
    const float* b_out  = (const float*)d_in[5];
    const float* w_mlp1 = (const float*)d_in[6];
    const float* b_mlp1 = (const float*)d_in[7];
    const float* w_mlp2 = (const float*)d_in[8];
    const float* b_mlp2 = (const float*)d_in[9];
    float* out = (float*)d_out;

    constexpr size_t MB = 1u << 20;
    char* w = (char*)d_ws;
    short*  xp_t  = (short*)(w);              // 16MB, dead after mgemm<0>
    short*  qb    = (short*)(w + 16 * MB);    // 48MB q/k/v, dead after attn_k
    short*  winb  = (short*)(w + 64 * MB);    // 21.5MB, dead after mgemm<1>
    float*  yb    = (float*)(w + 88 * MB);    // 32MB raw y, live to end
    short*  y_t   = (short*)(w + 120 * MB);   // 16MB
    short*  h_t   = (short*)(w);              // 64MB overlay [0,64)
    float2* yst   = (float2*)(w + 136 * MB);  // 8KB stats
    short*  wqb   = (short*)(w + 137 * MB);
    short*  wob   = wqb + 196608;
    short*  wm1b  = wob + 65536;
    short*  wm2b  = wm1b + 262144;

    const size_t SZ = (size_t)B_ * C_ * L_;

    wconv_k<<<384, 256, 0, stream>>>(w_qkv, w_out, w_mlp1, w_mlp2, wqb, wob, wm1b, wm2b);
    prep_k <<<dim3(128, 4, B_), 256, 0, stream>>>(x, pos, nullptr, xp_t);

    mgemm<0><<<dim3(64, 6, B_), 256, 0, stream>>>(wqb, xp_t, b_qkv, nullptr, qb);
    attn_k  <<<dim3(NWIN, NH, B_), 256, 0, stream>>>(qb, qb + SZ, qb + 2 * SZ, winb);
    mgemm<1><<<dim3(64, 2, B_), 256, 0, stream>>>(wob, winb, b_out, x, yb);
    stats_k <<<B_ * C_, 256, 0, stream>>>(yb, yst);
    prep_k  <<<dim3(128, 4, B_), 256, 0, stream>>>(yb, nullptr, yst, y_t);
    mgemm<2><<<dim3(64, 8, B_), 256, 0, stream>>>(wm1b, y_t, b_mlp1, nullptr, h_t);
    mgemm<3><<<dim3(64, 2, B_), 256, 0, stream>>>(wm2b, h_t, b_mlp2, nullptr, out);
    norm_k  <<<B_ * C_, 256, 0, stream>>>(out, yb, yst, out);
}